// Round 4
// baseline (343.310 us; speedup 1.0000x reference)
//
#include <hip/hip_runtime.h>
#include <stdint.h>

#define NEG  16
#define EPSL 1e-11f

typedef _Float16 h2 __attribute__((ext_vector_type(2)));
typedef _Float16 h8 __attribute__((ext_vector_type(8)));
typedef __attribute__((ext_vector_type(4))) float f32x4;

#if __has_builtin(__builtin_amdgcn_fdot2)
#define FDOT2(a, b, c) __builtin_amdgcn_fdot2((a), (b), (c), false)
#else
#define FDOT2(a, b, c) fmaf((float)(a)[0], (float)(b)[0], \
                         fmaf((float)(a)[1], (float)(b)[1], (c)))
#endif

// ---------------- helpers ----------------
__device__ __forceinline__ uint32_t pk2h(float a, float b) {
    union { h2 h; uint32_t u; } t;
    t.h = (h2){ (_Float16)a, (_Float16)b };
    return t.u;
}

__device__ __forceinline__ uint64_t sm64(uint64_t x) {
    x += 0x9E3779B97F4A7C15ULL;
    x = (x ^ (x >> 30)) * 0xBF58476D1CE4E5B9ULL;
    x = (x ^ (x >> 27)) * 0x94D049BB133111EBULL;
    return x ^ (x >> 31);
}

__device__ __forceinline__ uint32_t rowz_of(uint32_t f, int dim, int S, int s) {
    uint32_t b = f & 31u;
    uint32_t r = f >> 5;
    uint32_t d, h, w;
    if (dim == 0) {
        w = r & 7u; h = (r >> 3) & 7u; d = (r >> 6) + (uint32_t)s;
    } else if (dim == 1) {
        w = r & 7u; uint32_t q = r >> 3;
        h = q % (uint32_t)S + (uint32_t)s; d = q / (uint32_t)S;
    } else {
        w = r % (uint32_t)S + (uint32_t)s; uint32_t q = r / (uint32_t)S;
        h = q & 7u; d = q >> 3;
    }
    return b * 512u + d * 64u + h * 8u + w;
}

// 32-channel fp16 dot: cf = 16 x h2 ctx regs, rp = row pointer (64B, 16B-aligned)
__device__ __forceinline__ float dot32(const h2* cf, const uint16_t* rp) {
    float r = 0.f;
    #pragma unroll
    for (int i = 0; i < 4; i++) {
        union { uint4 u; h2 h[4]; } v;
        v.u = *(const uint4*)(rp + i * 8);
        r = FDOT2(cf[i * 4 + 0], v.h[0], r);
        r = FDOT2(cf[i * 4 + 1], v.h[1], r);
        r = FDOT2(cf[i * 4 + 2], v.h[2], r);
        r = FDOT2(cf[i * 4 + 3], v.h[3], r);
    }
    return r;
}

// ---------------- kernels ----------------
__global__ void k_init(float* sums, int* cnts) {
    int t = threadIdx.x;
    if (t < 18) { sums[t] = 0.f; cnts[t] = 0; }
}

// Transpose+cast to fp16. z -> zhf in MFMA A-fragment order:
//   zhf[(mt*8+ks)*512 + lq*128 + lm*8 + j] = z_h[m=mt*16+lm][ch=ks*32+lq*8+j]
// c -> cTh row-major [row][ch].
__global__ __launch_bounds__(256) void k_prep(const float* __restrict__ z,
                                              const float* __restrict__ c,
                                              uint16_t* __restrict__ zhf,
                                              uint16_t* __restrict__ cTh) {
    __shared__ float tile[32][33];
    const int t = threadIdx.x;
    const int b = blockIdx.z & 31;
    const int isC = blockIdx.z >> 5;
    const float* src = isC ? c : z;
    const int p0 = blockIdx.x * 32, ch0 = blockIdx.y * 32;
    const float* sb = src + (size_t)b * 131072;
    const int pl = t & 31, cl = t >> 5;
    #pragma unroll
    for (int i = 0; i < 4; i++)
        tile[cl + i * 8][pl] = sb[(ch0 + cl + i * 8) * 512 + p0 + pl];
    __syncthreads();
    const int pw = t >> 3, cp = (t & 7) * 4;
    uint32_t lo = pk2h(tile[cp + 0][pw], tile[cp + 1][pw]);
    uint32_t hi = pk2h(tile[cp + 2][pw], tile[cp + 3][pw]);
    const int m = b * 512 + p0 + pw;
    const int ch = ch0 + cp;
    if (isC) {
        *(uint2*)(cTh + (size_t)m * 256 + ch) = make_uint2(lo, hi);
    } else {
        const int mt = m >> 4, lm = m & 15;
        const int ks = ch >> 5, lq = (ch >> 3) & 3, jj = ch & 7;
        *(uint2*)(zhf + (size_t)(mt * 8 + ks) * 512 + lq * 128 + lm * 8 + jj) =
            make_uint2(lo, hi);
    }
}

// W [kk][o][c] f32 -> Whf fp16 in MFMA B-fragment order:
//   Whf[gid*512 + lane*8 + j] = W[kk][ot*16+lm][ks*32+lq*8+j], gid=(kk*16+ot)*8+ks
__global__ __launch_bounds__(256) void k_castw(const float* __restrict__ W,
                                               uint16_t* __restrict__ Whf) {
    const int gid = blockIdx.x * 4 + (threadIdx.x >> 6);
    const int lane = threadIdx.x & 63;
    const int kk = gid >> 7, rem = gid & 127;
    const int ot = rem >> 3, ks = rem & 7;
    const int o = ot * 16 + (lane & 15);
    const int cc = ks * 32 + (lane >> 4) * 8;
    const float* src = W + ((size_t)kk * 256 + o) * 256 + cc;
    float4 v0 = *(const float4*)src;
    float4 v1 = *(const float4*)(src + 4);
    uint4 out = make_uint4(pk2h(v0.x, v0.y), pk2h(v0.z, v0.w),
                           pk2h(v1.x, v1.y), pk2h(v1.z, v1.w));
    *(uint4*)(Whf + (size_t)gid * 512 + lane * 8) = out;
}

// ZWh[kk][m][o] via fp16 MFMA; fragment loads coalesced (base + lane*8).
// Wave: 2 m-tiles x 256 o. Writeback staged through wave-private LDS so
// global stores are 8 coalesced dwordx4 per tile (was 64 scattered b16).
__global__ __launch_bounds__(256) void k_gemm(const uint16_t* __restrict__ zhf,
                                              const uint16_t* __restrict__ Whf,
                                              uint16_t* __restrict__ ZWh) {
    __shared__ uint16_t lbuf[4][4096];          // 4 waves x 8 KiB
    const int kk = blockIdx.y;
    const int lane = threadIdx.x & 63;
    const int wv = threadIdx.x >> 6;
    const int mt0 = blockIdx.x * 8 + wv * 2;
    const int lm = lane & 15, lq = lane >> 4;
    const uint16_t* B0 = Whf + (size_t)kk * 128 * 512 + lane * 8;
    const uint16_t* A0 = zhf + (size_t)mt0 * 8 * 512 + lane * 8;

    f32x4 acc[2][16];
    #pragma unroll
    for (int i = 0; i < 2; i++)
        #pragma unroll
        for (int jj = 0; jj < 16; jj++) acc[i][jj] = (f32x4){0.f, 0.f, 0.f, 0.f};

    #pragma unroll
    for (int ks = 0; ks < 8; ks++) {
        h8 a0 = *(const h8*)(A0 + ks * 512);
        h8 a1 = *(const h8*)(A0 + (8 + ks) * 512);
        #pragma unroll
        for (int ot = 0; ot < 16; ot++) {
            h8 bv = *(const h8*)(B0 + (size_t)(ot * 8 + ks) * 512);
            acc[0][ot] = __builtin_amdgcn_mfma_f32_16x16x32_f16(a0, bv, acc[0][ot], 0, 0, 0);
            acc[1][ot] = __builtin_amdgcn_mfma_f32_16x16x32_f16(a1, bv, acc[1][ot], 0, 0, 0);
        }
    }
    uint16_t* zwk = ZWh + (size_t)kk * 16384 * 256;
    uint16_t* Lb = lbuf[wv];
    #pragma unroll
    for (int t2 = 0; t2 < 2; t2++) {
        // C/D layout: row=lq*4+r (within 16), col=ot*16+lm
        #pragma unroll
        for (int ot = 0; ot < 16; ot++)
            #pragma unroll
            for (int r = 0; r < 4; r++) {
                union { _Float16 h; uint16_t u; } cv;
                cv.h = (_Float16)acc[t2][ot][r];
                Lb[(lq * 4 + r) * 256 + ot * 16 + lm] = cv.u;
            }
        // wave-private region: no barrier needed, compiler inserts lgkmcnt waits
        uint4* dst = (uint4*)(zwk + (size_t)(mt0 + t2) * 16 * 256);
        const uint4* Lr = (const uint4*)Lb;
        #pragma unroll
        for (int i = 0; i < 8; i++)
            dst[i * 64 + lane] = Lr[i * 64 + lane];
    }
}

// Score: 8-lane group per position (8 positions/wave in parallel), 2 iters ->
// 64 positions/block. lane q = lane&7: channels 32q..32q+31, negatives n=q,q+8.
__global__ __launch_bounds__(256) void k_score(const uint16_t* __restrict__ ZWh,
                                               const uint16_t* __restrict__ cTh,
                                               const int* __restrict__ ign,
                                               float* sums, int* cnts) {
    int bid = blockIdx.x;
    int kk = 0, cum = 0;
    for (;;) { int nb = 96 * (6 - kk); if (bid < cum + nb) break; cum += nb; kk++; }
    const int S = 6 - kk, T = S * 2048, s = kk + 2;
    const uint16_t* ZW = ZWh + (size_t)kk * 16384 * 256;

    const uint32_t fbase = (uint32_t)(bid - cum) * 64u;
    const int dim = (int)(fbase / (uint32_t)T);
    const uint32_t fb = fbase - (uint32_t)dim * (uint32_t)T;
    const int term = dim * 6 + kk;

    const int t = threadIdx.x, lane = t & 63, wv = t >> 6;
    const int q = lane & 7, g = lane >> 3;
    __shared__ float snll[32];
    __shared__ int   smsk[32];

    float accn = 0.f; int accm = 0;

    #pragma unroll
    for (int j = 0; j < 2; j++) {
        uint32_t f = fb + (uint32_t)(wv * 16 + j * 8 + g);
        uint32_t b = f & 31u, r = f >> 5;
        uint32_t d, h, w;
        if (dim == 0)      { w = r & 7u; h = (r >> 3) & 7u; d = r >> 6; }
        else if (dim == 1) { w = r & 7u; uint32_t qq = r >> 3; h = qq % (uint32_t)S; d = qq / (uint32_t)S; }
        else               { w = r % (uint32_t)S; uint32_t qq = r / (uint32_t)S; h = qq & 7u; d = qq >> 3; }
        uint32_t pc = d * 64u + h * 8u + w;
        uint32_t pz = pc + (dim == 0 ? (uint32_t)s * 64u : dim == 1 ? (uint32_t)s * 8u : (uint32_t)s);
        uint32_t rowc = b * 512u + pc;
        uint32_t rowz = b * 512u + pz;

        // two negatives per lane: n = q and n = q+8 (same per-position RNG stream)
        uint64_t x0 = sm64(((uint64_t)term << 40) + (uint64_t)f * 16u + (uint64_t)q);
        uint64_t x1 = sm64(((uint64_t)term << 40) + (uint64_t)f * 16u + (uint64_t)(q + 8));
        uint32_t nr0 = rowz_of((uint32_t)(x0 >> 32) % (uint32_t)T, dim, S, s);
        uint32_t nr1 = rowz_of((uint32_t)(x1 >> 32) % (uint32_t)T, dim, S, s);

        // ctx channels 32q..32q+31
        h2 cf[16];
        const uint16_t* cp_ = cTh + (size_t)rowc * 256 + q * 32;
        #pragma unroll
        for (int i = 0; i < 4; i++) {
            union { uint4 u; h2 h[4]; } v;
            v.u = *(const uint4*)(cp_ + i * 8);
            cf[i * 4 + 0] = v.h[0]; cf[i * 4 + 1] = v.h[1];
            cf[i * 4 + 2] = v.h[2]; cf[i * 4 + 3] = v.h[3];
        }

        float sc[17];
        sc[0] = dot32(cf, ZW + (size_t)rowz * 256 + q * 32);
        #pragma unroll
        for (int n = 0; n < 8; n++) {
            uint32_t rn = (uint32_t)__shfl((int)nr0, (lane & 56) + n, 64);
            sc[n + 1] = dot32(cf, ZW + (size_t)rn * 256 + q * 32);
        }
        #pragma unroll
        for (int n = 0; n < 8; n++) {
            uint32_t rn = (uint32_t)__shfl((int)nr1, (lane & 56) + n, 64);
            sc[n + 9] = dot32(cf, ZW + (size_t)rn * 256 + q * 32);
        }
        // 3-stage butterfly within the 8-lane group
        #pragma unroll
        for (int st = 1; st < 8; st <<= 1)
            #pragma unroll
            for (int i = 0; i < 17; i++)
                sc[i] += __shfl_xor(sc[i], st, 64);

        float mx = sc[0];
        #pragma unroll
        for (int i = 1; i < 17; i++) mx = fmaxf(mx, sc[i]);
        float e0 = __expf(sc[0] - mx);
        float sum = e0;
        #pragma unroll
        for (int i = 1; i < 17; i++) sum += __expf(sc[i] - mx);
        float nll = -__logf(e0 / sum + EPSL);

        int m = (ign[rowc] + ign[rowz]) == 0;
        accn += m ? nll : 0.f;
        accm += m;
    }

    if (q == 0) { snll[wv * 8 + g] = accn; smsk[wv * 8 + g] = accm; }
    __syncthreads();
    if (t == 0) {
        float sm = 0.f; int cm = 0;
        #pragma unroll
        for (int i = 0; i < 32; i++) { sm += snll[i]; cm += smsk[i]; }
        atomicAdd(&sums[term], sm);
        atomicAdd(&cnts[term], cm);
    }
}

__global__ void k_final(const float* __restrict__ sums, const int* __restrict__ cnts,
                        float* __restrict__ out) {
    if (threadIdx.x == 0) {
        float tot = 0.f;
        #pragma unroll
        for (int i = 0; i < 18; i++) tot += sums[i] / (float)cnts[i];
        out[0] = tot / 18.f;
    }
}

// ---------------- launch ----------------
extern "C" void kernel_launch(void* const* d_in, const int* in_sizes, int n_in,
                              void* d_out, int out_size, void* d_ws, size_t ws_size,
                              hipStream_t stream) {
    const float* z   = (const float*)d_in[0];
    const float* c   = (const float*)d_in[1];
    const int*   ign = (const int*)d_in[2];
    const float* Wk  = (const float*)d_in[3];

    float* sums = (float*)d_ws;
    int*   cnts = (int*)((char*)d_ws + 128);
    uint16_t* zhf = (uint16_t*)((char*)d_ws + 1024);    // 8 MiB (A-fragment order)
    uint16_t* cTh = zhf + (size_t)16384 * 256;          // 8 MiB (row major)
    uint16_t* Whf = cTh + (size_t)16384 * 256;          // 768 KiB (B-fragment order)
    uint16_t* ZWh = Whf + (size_t)6 * 65536;            // 48 MiB

    hipLaunchKernelGGL(k_init, dim3(1), dim3(64), 0, stream, sums, cnts);
    hipLaunchKernelGGL(k_prep, dim3(16, 8, 64), dim3(256), 0, stream, z, c, zhf, cTh);
    hipLaunchKernelGGL(k_castw, dim3(192), dim3(256), 0, stream, Wk, Whf);
    hipLaunchKernelGGL(k_gemm, dim3(128, 6), dim3(256), 0, stream, zhf, Whf, ZWh);
    hipLaunchKernelGGL(k_score, dim3(2016), dim3(256), 0, stream, ZWh, cTh, ign, sums, cnts);
    hipLaunchKernelGGL(k_final, dim3(1), dim3(1), 0, stream, sums, cnts, (float*)d_out);
}

// Round 5
// 271.572 us; speedup vs baseline: 1.2642x; 1.2642x over previous
//
#include <hip/hip_runtime.h>
#include <stdint.h>

#define EPSL 1e-11f

typedef _Float16 h2 __attribute__((ext_vector_type(2)));
typedef _Float16 h8 __attribute__((ext_vector_type(8)));
typedef __attribute__((ext_vector_type(4))) float f32x4;

// ---------------- helpers ----------------
__device__ __forceinline__ uint32_t pk2h(float a, float b) {
    union { h2 h; uint32_t u; } t;
    t.h = (h2){ (_Float16)a, (_Float16)b };
    return t.u;
}
__device__ __forceinline__ uint16_t f2h(float a) {
    union { _Float16 h; uint16_t u; } t; t.h = (_Float16)a; return t.u;
}

__device__ __forceinline__ uint64_t sm64(uint64_t x) {
    x += 0x9E3779B97F4A7C15ULL;
    x = (x ^ (x >> 30)) * 0xBF58476D1CE4E5B9ULL;
    x = (x ^ (x >> 27)) * 0x94D049BB133111EBULL;
    return x ^ (x >> 31);
}

__device__ __forceinline__ uint32_t rowz_of(uint32_t f, int dim, int S, int s) {
    uint32_t b = f & 31u;
    uint32_t r = f >> 5;
    uint32_t d, h, w;
    if (dim == 0) {
        w = r & 7u; h = (r >> 3) & 7u; d = (r >> 6) + (uint32_t)s;
    } else if (dim == 1) {
        w = r & 7u; uint32_t q = r >> 3;
        h = q % (uint32_t)S + (uint32_t)s; d = q / (uint32_t)S;
    } else {
        w = r % (uint32_t)S + (uint32_t)s; uint32_t q = r / (uint32_t)S;
        h = q & 7u; d = q >> 3;
    }
    return b * 512u + d * 64u + h * 8u + w;
}

// ---------------- kernels ----------------
__global__ void k_init(float* sums, int* cnts) {
    int t = threadIdx.x;
    if (t < 18) { sums[t] = 0.f; cnts[t] = 0; }
}

// Transpose+cast to fp16, ROW-MAJOR [row=b*512+p][ch] for both z and c.
// Block: 64 p x 32 ch tile. 16B stores.
__global__ __launch_bounds__(256) void k_prep(const float* __restrict__ z,
                                              const float* __restrict__ c,
                                              uint16_t* __restrict__ zh,
                                              uint16_t* __restrict__ cTh) {
    __shared__ float tile[32][65];
    const int t = threadIdx.x;
    const int b = blockIdx.z & 31, isC = blockIdx.z >> 5;
    const float* src = (isC ? c : z) + (size_t)b * 131072;
    const int p0 = blockIdx.x * 64, ch0 = blockIdx.y * 32;
    const int pl = t & 63, cl0 = t >> 6;
    #pragma unroll
    for (int i = 0; i < 8; i++)
        tile[cl0 + i * 4][pl] = src[(ch0 + cl0 + i * 4) * 512 + p0 + pl];
    __syncthreads();
    const int ml = t >> 2, ck = (t & 3) * 8;
    uint4 o;
    o.x = pk2h(tile[ck + 0][ml], tile[ck + 1][ml]);
    o.y = pk2h(tile[ck + 2][ml], tile[ck + 3][ml]);
    o.z = pk2h(tile[ck + 4][ml], tile[ck + 5][ml]);
    o.w = pk2h(tile[ck + 6][ml], tile[ck + 7][ml]);
    uint16_t* dst = isC ? cTh : zh;
    *(uint4*)(dst + (size_t)(b * 512 + p0 + ml) * 256 + ch0 + ck) = o;
}

// W [kk][o][c] f32 -> Whf fp16 in MFMA B-fragment order:
//   Whf[gid*512 + lane*8 + j] = W[kk][ot*16+lm][ks*32+lq*8+j], gid=(kk*16+ot)*8+ks
__global__ __launch_bounds__(256) void k_castw(const float* __restrict__ W,
                                               uint16_t* __restrict__ Whf) {
    const int gid = blockIdx.x * 4 + (threadIdx.x >> 6);
    const int lane = threadIdx.x & 63;
    const int kk = gid >> 7, rem = gid & 127;
    const int ot = rem >> 3, ks = rem & 7;
    const int o = ot * 16 + (lane & 15);
    const int cc = ks * 32 + (lane >> 4) * 8;
    const float* src = W + ((size_t)kk * 256 + o) * 256 + cc;
    float4 v0 = *(const float4*)src;
    float4 v1 = *(const float4*)(src + 4);
    uint4 out = make_uint4(pk2h(v0.x, v0.y), pk2h(v0.z, v0.w),
                           pk2h(v1.x, v1.y), pk2h(v1.z, v1.w));
    *(uint4*)(Whf + (size_t)gid * 512 + lane * 8) = out;
}

// ZWh[kk][m][o]: 1 m-tile (16 rows) per wave, acc = 64 VGPR, 4 waves/SIMD.
// A-fragment from row-major zh; B-fragment from pre-swizzled Whf.
__global__ __launch_bounds__(256, 4) void k_gemm(const uint16_t* __restrict__ zh,
                                                 const uint16_t* __restrict__ Whf,
                                                 uint16_t* __restrict__ ZWh) {
    __shared__ uint16_t lbuf[4][4096];
    const int kk = blockIdx.y;
    const int lane = threadIdx.x & 63, wv = threadIdx.x >> 6;
    const int mt = blockIdx.x * 4 + wv;            // 0..1023
    const int lm = lane & 15, lq = lane >> 4;
    const uint16_t* A0 = zh + (size_t)(mt * 16 + lm) * 256 + lq * 8;
    const uint16_t* B0 = Whf + (size_t)kk * 65536 + lane * 8;

    f32x4 acc[16];
    #pragma unroll
    for (int i = 0; i < 16; i++) acc[i] = (f32x4){0.f, 0.f, 0.f, 0.f};

    #pragma unroll
    for (int ks = 0; ks < 8; ks++) {
        h8 a = *(const h8*)(A0 + ks * 32);
        #pragma unroll
        for (int ot = 0; ot < 16; ot++) {
            h8 bv = *(const h8*)(B0 + (size_t)(ot * 8 + ks) * 512);
            acc[ot] = __builtin_amdgcn_mfma_f32_16x16x32_f16(a, bv, acc[ot], 0, 0, 0);
        }
    }
    // stage 16x256 tile in wave-private LDS, then 8 coalesced dwordx4 stores
    uint16_t* Lb = lbuf[wv];
    #pragma unroll
    for (int ot = 0; ot < 16; ot++)
        #pragma unroll
        for (int r = 0; r < 4; r++)
            Lb[(lq * 4 + r) * 256 + ot * 16 + lm] = f2h(acc[ot][r]);
    uint4* dst = (uint4*)(ZWh + ((size_t)kk * 16384 + (size_t)mt * 16) * 256);
    const uint4* Lr = (const uint4*)Lb;
    #pragma unroll
    for (int i = 0; i < 8; i++)
        dst[i * 64 + lane] = Lr[i * 64 + lane];
}

// Score with SHARED negatives: one wave = one group of 16 batch-consecutive
// positions (same spatial site), sharing 16 sampled negative rows.
// S_neg = ctx(16x256) . negs^T  (8 MFMAs), diag(ctx . pos^T) (8 MFMAs),
// then LDS round-trip + per-lane softmax (lane lm <-> position lm, x4 redundant).
__global__ __launch_bounds__(256, 4) void k_score(const uint16_t* __restrict__ ZWh,
                                                  const uint16_t* __restrict__ cTh,
                                                  const int* __restrict__ ign,
                                                  float* sums, int* cnts) {
    __shared__ float sbuf[4][16 * 17 + 16];
    int bid = blockIdx.x;
    int kk = 0, cum = 0;
    for (;;) { int nb = 96 * (6 - kk); if (bid < cum + nb) break; cum += nb; kk++; }
    const int S = 6 - kk, T = S * 2048, s = kk + 2;
    const uint16_t* ZW = ZWh + (size_t)kk * 16384 * 256;

    const uint32_t fbase = (uint32_t)(bid - cum) * 64u;
    const int dim = (int)(fbase / (uint32_t)T);
    const uint32_t fb = fbase - (uint32_t)dim * (uint32_t)T;
    const int term = dim * 6 + kk;

    const int t = threadIdx.x, lane = t & 63, wv = t >> 6;
    const int lm = lane & 15, lq = lane >> 4;
    const uint32_t fg = fb + (uint32_t)(wv * 16);   // group base
    const uint32_t gid = fg >> 4;                   // group id within term

    // this lane's position p = lm  ->  f = fg + lm
    uint32_t f = fg + (uint32_t)lm;
    uint32_t b = f & 31u, r = f >> 5;
    uint32_t d, h, w;
    if (dim == 0)      { w = r & 7u; h = (r >> 3) & 7u; d = r >> 6; }
    else if (dim == 1) { w = r & 7u; uint32_t qq = r >> 3; h = qq % (uint32_t)S; d = qq / (uint32_t)S; }
    else               { w = r % (uint32_t)S; uint32_t qq = r / (uint32_t)S; h = qq & 7u; d = qq >> 3; }
    uint32_t pc = d * 64u + h * 8u + w;
    uint32_t pz = pc + (dim == 0 ? (uint32_t)s * 64u : dim == 1 ? (uint32_t)s * 8u : (uint32_t)s);
    uint32_t rowc = b * 512u + pc;
    uint32_t rowz = b * 512u + pz;

    // shared negative n = lm for this group
    uint64_t x = sm64(((uint64_t)term << 40) + (uint64_t)gid * 16u + (uint64_t)lm);
    uint32_t nrow = rowz_of((uint32_t)(x >> 32) % (uint32_t)T, dim, S, s);

    const uint16_t* ap = cTh + (size_t)rowc * 256 + lq * 8;   // A: ctx row lm
    const uint16_t* np = ZW + (size_t)nrow * 256 + lq * 8;    // B: neg row lm
    const uint16_t* pp = ZW + (size_t)rowz * 256 + lq * 8;    // B: pos row lm

    f32x4 an = (f32x4){0.f, 0.f, 0.f, 0.f};
    f32x4 apo = (f32x4){0.f, 0.f, 0.f, 0.f};
    #pragma unroll
    for (int ks = 0; ks < 8; ks++) {
        h8 a  = *(const h8*)(ap + ks * 32);
        h8 bn = *(const h8*)(np + ks * 32);
        an = __builtin_amdgcn_mfma_f32_16x16x32_f16(a, bn, an, 0, 0, 0);
    }
    #pragma unroll
    for (int ks = 0; ks < 8; ks++) {
        h8 a  = *(const h8*)(ap + ks * 32);
        h8 bp = *(const h8*)(pp + ks * 32);
        apo = __builtin_amdgcn_mfma_f32_16x16x32_f16(a, bp, apo, 0, 0, 0);
    }

    // stage scores: Sb[m*17+n] = neg score, Sb[272+m] = positive (diagonal)
    float* Sb = sbuf[wv];
    #pragma unroll
    for (int rr = 0; rr < 4; rr++)
        Sb[(lq * 4 + rr) * 17 + lm] = an[rr];       // row=lq*4+rr, col=lm
    if ((lm >> 2) == lq) Sb[272 + lm] = apo[lm & 3];

    // softmax-NLL for position p = lm (4x redundant across lq)
    float dpos = Sb[272 + lm];
    float mx = dpos;
    float scn[16];
    #pragma unroll
    for (int n = 0; n < 16; n++) { scn[n] = Sb[lm * 17 + n]; mx = fmaxf(mx, scn[n]); }
    float e0 = __expf(dpos - mx), sum = e0;
    #pragma unroll
    for (int n = 0; n < 16; n++) sum += __expf(scn[n] - mx);
    float nll = -__logf(e0 / sum + EPSL);

    int mok = (ign[rowc] + ign[rowz]) == 0;
    float v = mok ? nll : 0.f;
    float cm = mok ? 1.f : 0.f;
    #pragma unroll
    for (int st = 1; st < 64; st <<= 1) {
        v  += __shfl_xor(v, st, 64);
        cm += __shfl_xor(cm, st, 64);
    }
    if (lane == 0) {
        atomicAdd(&sums[term], v * 0.25f);                 // 4x quad redundancy
        atomicAdd(&cnts[term], (int)(cm * 0.25f + 0.5f));
    }
}

__global__ void k_final(const float* __restrict__ sums, const int* __restrict__ cnts,
                        float* __restrict__ out) {
    if (threadIdx.x == 0) {
        float tot = 0.f;
        #pragma unroll
        for (int i = 0; i < 18; i++) tot += sums[i] / (float)cnts[i];
        out[0] = tot / 18.f;
    }
}

// ---------------- launch ----------------
extern "C" void kernel_launch(void* const* d_in, const int* in_sizes, int n_in,
                              void* d_out, int out_size, void* d_ws, size_t ws_size,
                              hipStream_t stream) {
    const float* z   = (const float*)d_in[0];
    const float* c   = (const float*)d_in[1];
    const int*   ign = (const int*)d_in[2];
    const float* Wk  = (const float*)d_in[3];

    float* sums = (float*)d_ws;
    int*   cnts = (int*)((char*)d_ws + 128);
    uint16_t* zh  = (uint16_t*)((char*)d_ws + 1024);    // 8 MiB row-major fp16
    uint16_t* cTh = zh  + (size_t)16384 * 256;          // 8 MiB row-major fp16
    uint16_t* Whf = cTh + (size_t)16384 * 256;          // 768 KiB B-fragment order
    uint16_t* ZWh = Whf + (size_t)6 * 65536;            // 48 MiB row-major fp16

    hipLaunchKernelGGL(k_init, dim3(1), dim3(64), 0, stream, sums, cnts);
    hipLaunchKernelGGL(k_prep, dim3(8, 8, 64), dim3(256), 0, stream, z, c, zh, cTh);
    hipLaunchKernelGGL(k_castw, dim3(192), dim3(256), 0, stream, Wk, Whf);
    hipLaunchKernelGGL(k_gemm, dim3(256, 6), dim3(256), 0, stream, zh, Whf, ZWh);
    hipLaunchKernelGGL(k_score, dim3(2016), dim3(256), 0, stream, ZWh, cTh, ign, sums, cnts);
    hipLaunchKernelGGL(k_final, dim3(1), dim3(1), 0, stream, sums, cnts, (float*)d_out);
}

// Round 6
// 242.118 us; speedup vs baseline: 1.4179x; 1.1216x over previous
//
#include <hip/hip_runtime.h>
#include <stdint.h>

#define EPSL 1e-11f

typedef _Float16 h2 __attribute__((ext_vector_type(2)));
typedef _Float16 h8 __attribute__((ext_vector_type(8)));
typedef __attribute__((ext_vector_type(4))) float f32x4;

// ---------------- helpers ----------------
__device__ __forceinline__ uint32_t pk2h(float a, float b) {
    union { h2 h; uint32_t u; } t;
    t.h = (h2){ (_Float16)a, (_Float16)b };
    return t.u;
}
__device__ __forceinline__ uint16_t f2h(float a) {
    union { _Float16 h; uint16_t u; } t; t.h = (_Float16)a; return t.u;
}

__device__ __forceinline__ uint64_t sm64(uint64_t x) {
    x += 0x9E3779B97F4A7C15ULL;
    x = (x ^ (x >> 30)) * 0xBF58476D1CE4E5B9ULL;
    x = (x ^ (x >> 27)) * 0x94D049BB133111EBULL;
    return x ^ (x >> 31);
}

__device__ __forceinline__ uint32_t rowz_of(uint32_t f, int dim, int S, int s) {
    uint32_t b = f & 31u;
    uint32_t r = f >> 5;
    uint32_t d, h, w;
    if (dim == 0) {
        w = r & 7u; h = (r >> 3) & 7u; d = (r >> 6) + (uint32_t)s;
    } else if (dim == 1) {
        w = r & 7u; uint32_t q = r >> 3;
        h = q % (uint32_t)S + (uint32_t)s; d = q / (uint32_t)S;
    } else {
        w = r % (uint32_t)S + (uint32_t)s; uint32_t q = r / (uint32_t)S;
        h = q & 7u; d = q >> 3;
    }
    return b * 512u + d * 64u + h * 8u + w;
}

// ---------------- kernels ----------------
// zero the 18x64 slot accumulators
__global__ void k_init(float* sums_s, int* cnts_s) {
    int t = blockIdx.x * 256 + threadIdx.x;
    if (t < 1152) { sums_s[t] = 0.f; cnts_s[t] = 0; }
}

// Transpose+cast to fp16, ROW-MAJOR [row=b*512+p][ch] for both z and c.
__global__ __launch_bounds__(256) void k_prep(const float* __restrict__ z,
                                              const float* __restrict__ c,
                                              uint16_t* __restrict__ zh,
                                              uint16_t* __restrict__ cTh) {
    __shared__ float tile[32][65];
    const int t = threadIdx.x;
    const int b = blockIdx.z & 31, isC = blockIdx.z >> 5;
    const float* src = (isC ? c : z) + (size_t)b * 131072;
    const int p0 = blockIdx.x * 64, ch0 = blockIdx.y * 32;
    const int pl = t & 63, cl0 = t >> 6;
    #pragma unroll
    for (int i = 0; i < 8; i++)
        tile[cl0 + i * 4][pl] = src[(ch0 + cl0 + i * 4) * 512 + p0 + pl];
    __syncthreads();
    const int ml = t >> 2, ck = (t & 3) * 8;
    uint4 o;
    o.x = pk2h(tile[ck + 0][ml], tile[ck + 1][ml]);
    o.y = pk2h(tile[ck + 2][ml], tile[ck + 3][ml]);
    o.z = pk2h(tile[ck + 4][ml], tile[ck + 5][ml]);
    o.w = pk2h(tile[ck + 6][ml], tile[ck + 7][ml]);
    uint16_t* dst = isC ? cTh : zh;
    *(uint4*)(dst + (size_t)(b * 512 + p0 + ml) * 256 + ch0 + ck) = o;
}

// W [kk][o][c] f32 -> Whf fp16 in MFMA B-fragment order
__global__ __launch_bounds__(256) void k_castw(const float* __restrict__ W,
                                               uint16_t* __restrict__ Whf) {
    const int gid = blockIdx.x * 4 + (threadIdx.x >> 6);
    const int lane = threadIdx.x & 63;
    const int kk = gid >> 7, rem = gid & 127;
    const int ot = rem >> 3, ks = rem & 7;
    const int o = ot * 16 + (lane & 15);
    const int cc = ks * 32 + (lane >> 4) * 8;
    const float* src = W + ((size_t)kk * 256 + o) * 256 + cc;
    float4 v0 = *(const float4*)src;
    float4 v1 = *(const float4*)(src + 4);
    uint4 out = make_uint4(pk2h(v0.x, v0.y), pk2h(v0.z, v0.w),
                           pk2h(v1.x, v1.y), pk2h(v1.z, v1.w));
    *(uint4*)(Whf + (size_t)gid * 512 + lane * 8) = out;
}

// ZWh[kk][m][o]: 1 m-tile (16 rows) per wave (unchanged from round 5)
__global__ __launch_bounds__(256, 4) void k_gemm(const uint16_t* __restrict__ zh,
                                                 const uint16_t* __restrict__ Whf,
                                                 uint16_t* __restrict__ ZWh) {
    __shared__ uint16_t lbuf[4][4096];
    const int kk = blockIdx.y;
    const int lane = threadIdx.x & 63, wv = threadIdx.x >> 6;
    const int mt = blockIdx.x * 4 + wv;
    const int lm = lane & 15, lq = lane >> 4;
    const uint16_t* A0 = zh + (size_t)(mt * 16 + lm) * 256 + lq * 8;
    const uint16_t* B0 = Whf + (size_t)kk * 65536 + lane * 8;

    f32x4 acc[16];
    #pragma unroll
    for (int i = 0; i < 16; i++) acc[i] = (f32x4){0.f, 0.f, 0.f, 0.f};

    #pragma unroll
    for (int ks = 0; ks < 8; ks++) {
        h8 a = *(const h8*)(A0 + ks * 32);
        #pragma unroll
        for (int ot = 0; ot < 16; ot++) {
            h8 bv = *(const h8*)(B0 + (size_t)(ot * 8 + ks) * 512);
            acc[ot] = __builtin_amdgcn_mfma_f32_16x16x32_f16(a, bv, acc[ot], 0, 0, 0);
        }
    }
    uint16_t* Lb = lbuf[wv];
    #pragma unroll
    for (int ot = 0; ot < 16; ot++)
        #pragma unroll
        for (int r = 0; r < 4; r++)
            Lb[(lq * 4 + r) * 256 + ot * 16 + lm] = f2h(acc[ot][r]);
    uint4* dst = (uint4*)(ZWh + ((size_t)kk * 16384 + (size_t)mt * 16) * 256);
    const uint4* Lr = (const uint4*)Lb;
    #pragma unroll
    for (int i = 0; i < 8; i++)
        dst[i * 64 + lane] = Lr[i * 64 + lane];
}

// Score: one wave = 16 batch-consecutive positions. 8 independent negative
// sets of 16 per group; positions 2j,2j+1 use set j (sharing factor 2).
// 9 MFMA chains; softmax via LDS; slotted atomics (64 slots/term).
__global__ __launch_bounds__(256) void k_score(const uint16_t* __restrict__ ZWh,
                                               const uint16_t* __restrict__ cTh,
                                               const int* __restrict__ ign,
                                               float* sums_s, int* cnts_s) {
    __shared__ float sbuf[4][288];
    __shared__ float wsum[4], wcnt[4];
    int bid = blockIdx.x;
    int kk = 0, cum = 0;
    for (;;) { int nb = 96 * (6 - kk); if (bid < cum + nb) break; cum += nb; kk++; }
    const int S = 6 - kk, T = S * 2048, s = kk + 2;
    const uint16_t* ZW = ZWh + (size_t)kk * 16384 * 256;

    const uint32_t fbase = (uint32_t)(bid - cum) * 64u;
    const int dim = (int)(fbase / (uint32_t)T);
    const uint32_t fb = fbase - (uint32_t)dim * (uint32_t)T;
    const int term = dim * 6 + kk;

    const int t = threadIdx.x, lane = t & 63, wv = t >> 6;
    const int lm = lane & 15, lq = lane >> 4;
    const uint32_t fg = fb + (uint32_t)(wv * 16);
    const uint32_t gid = fg >> 4;

    // lane's position p = lm -> dim-local flat f = fg + lm
    uint32_t f = fg + (uint32_t)lm;
    uint32_t b = f & 31u, r = f >> 5;
    uint32_t d, h, w;
    if (dim == 0)      { w = r & 7u; h = (r >> 3) & 7u; d = r >> 6; }
    else if (dim == 1) { w = r & 7u; uint32_t qq = r >> 3; h = qq % (uint32_t)S; d = qq / (uint32_t)S; }
    else               { w = r % (uint32_t)S; uint32_t qq = r / (uint32_t)S; h = qq & 7u; d = qq >> 3; }
    uint32_t pc = d * 64u + h * 8u + w;
    uint32_t pz = pc + (dim == 0 ? (uint32_t)s * 64u : dim == 1 ? (uint32_t)s * 8u : (uint32_t)s);
    uint32_t rowc = b * 512u + pc;
    uint32_t rowz = b * 512u + pz;

    // 8 negative sets; set j, neg index lm (same for all lq -> valid B-fragment)
    const uint16_t* np[8];
    #pragma unroll
    for (int j = 0; j < 8; j++) {
        uint64_t x = sm64(((uint64_t)term << 40) +
                          (uint64_t)gid * 128u + (uint64_t)(j * 16 + lm));
        uint32_t nrow = rowz_of((uint32_t)(x >> 32) % (uint32_t)T, dim, S, s);
        np[j] = ZW + (size_t)nrow * 256 + lq * 8;
    }
    const uint16_t* ap = cTh + (size_t)rowc * 256 + lq * 8;
    const uint16_t* pp = ZW + (size_t)rowz * 256 + lq * 8;

    f32x4 accp = (f32x4){0.f, 0.f, 0.f, 0.f};
    f32x4 accn[8];
    #pragma unroll
    for (int j = 0; j < 8; j++) accn[j] = (f32x4){0.f, 0.f, 0.f, 0.f};

    #pragma unroll
    for (int ks = 0; ks < 8; ks++) {
        h8 a = *(const h8*)(ap + ks * 32);
        accp = __builtin_amdgcn_mfma_f32_16x16x32_f16(a, *(const h8*)(pp + ks * 32), accp, 0, 0, 0);
        #pragma unroll
        for (int j = 0; j < 8; j++)
            accn[j] = __builtin_amdgcn_mfma_f32_16x16x32_f16(
                a, *(const h8*)(np[j] + ks * 32), accn[j], 0, 0, 0);
    }

    // stage: position p=lq*4+rr uses set j=p>>1. From accn[j], rows 2j,2j+1
    // -> lanes with lq==j>>1 store regs rr=(j&1)*2, (j&1)*2+1.
    float* Sb = sbuf[wv];
    #pragma unroll
    for (int j = 0; j < 8; j++) {
        const int rr0 = (j & 1) * 2;
        if (lq == (j >> 1)) {
            Sb[(lq * 4 + rr0) * 17 + lm]     = accn[j][rr0];
            Sb[(lq * 4 + rr0 + 1) * 17 + lm] = accn[j][rr0 + 1];
        }
    }
    if ((lm >> 2) == lq) Sb[272 + lm] = accp[lm & 3];

    // softmax-NLL for position p = lm (4x redundant across lq)
    float dpos = Sb[272 + lm];
    float mx = dpos;
    float scn[16];
    #pragma unroll
    for (int n = 0; n < 16; n++) { scn[n] = Sb[lm * 17 + n]; mx = fmaxf(mx, scn[n]); }
    float e0 = __expf(dpos - mx), sum = e0;
    #pragma unroll
    for (int n = 0; n < 16; n++) sum += __expf(scn[n] - mx);
    float nll = -__logf(e0 / sum + EPSL);

    int mok = (ign[rowc] + ign[rowz]) == 0;
    float v = mok ? nll : 0.f;
    float cm = mok ? 1.f : 0.f;
    #pragma unroll
    for (int st = 1; st < 64; st <<= 1) {
        v  += __shfl_xor(v, st, 64);
        cm += __shfl_xor(cm, st, 64);
    }
    if (lane == 0) { wsum[wv] = v * 0.25f; wcnt[wv] = cm * 0.25f; }
    __syncthreads();
    if (t == 0) {
        float sv = wsum[0] + wsum[1] + wsum[2] + wsum[3];
        float cv = wcnt[0] + wcnt[1] + wcnt[2] + wcnt[3];
        int slot = blockIdx.x & 63;
        atomicAdd(&sums_s[term * 64 + slot], sv);
        atomicAdd(&cnts_s[term * 64 + slot], (int)(cv + 0.5f));
    }
}

__global__ void k_final(const float* __restrict__ sums_s, const int* __restrict__ cnts_s,
                        float* __restrict__ out) {
    __shared__ float ratio[18];
    int t = threadIdx.x;
    if (t < 18) {
        float sv = 0.f; int cv = 0;
        #pragma unroll 8
        for (int i = 0; i < 64; i++) { sv += sums_s[t * 64 + i]; cv += cnts_s[t * 64 + i]; }
        ratio[t] = sv / (float)cv;
    }
    __syncthreads();
    if (t == 0) {
        float tot = 0.f;
        #pragma unroll
        for (int i = 0; i < 18; i++) tot += ratio[i];
        out[0] = tot / 18.f;
    }
}

// ---------------- launch ----------------
extern "C" void kernel_launch(void* const* d_in, const int* in_sizes, int n_in,
                              void* d_out, int out_size, void* d_ws, size_t ws_size,
                              hipStream_t stream) {
    const float* z   = (const float*)d_in[0];
    const float* c   = (const float*)d_in[1];
    const int*   ign = (const int*)d_in[2];
    const float* Wk  = (const float*)d_in[3];

    float* sums_s = (float*)d_ws;                           // 18*64 floats
    int*   cnts_s = (int*)((char*)d_ws + 4608);             // 18*64 ints
    uint16_t* zh  = (uint16_t*)((char*)d_ws + 65536);       // 8 MiB row-major fp16
    uint16_t* cTh = zh  + (size_t)16384 * 256;              // 8 MiB row-major fp16
    uint16_t* Whf = cTh + (size_t)16384 * 256;              // 768 KiB B-frag order
    uint16_t* ZWh = Whf + (size_t)6 * 65536;                // 48 MiB row-major fp16

    hipLaunchKernelGGL(k_init, dim3(5), dim3(256), 0, stream, sums_s, cnts_s);
    hipLaunchKernelGGL(k_prep, dim3(8, 8, 64), dim3(256), 0, stream, z, c, zh, cTh);
    hipLaunchKernelGGL(k_castw, dim3(192), dim3(256), 0, stream, Wk, Whf);
    hipLaunchKernelGGL(k_gemm, dim3(256, 6), dim3(256), 0, stream, zh, Whf, ZWh);
    hipLaunchKernelGGL(k_score, dim3(2016), dim3(256), 0, stream, ZWh, cTh, ign, sums_s, cnts_s);
    hipLaunchKernelGGL(k_final, dim3(1), dim3(64), 0, stream, sums_s, cnts_s, (float*)d_out);
}

// Round 7
// 195.055 us; speedup vs baseline: 1.7601x; 1.2413x over previous
//
#include <hip/hip_runtime.h>
#include <stdint.h>

#define EPSL 1e-11f

typedef _Float16 h2 __attribute__((ext_vector_type(2)));
typedef _Float16 h8 __attribute__((ext_vector_type(8)));
typedef __attribute__((ext_vector_type(4))) float f32x4;
typedef __attribute__((ext_vector_type(16))) float f32x16;

// ---------------- helpers ----------------
__device__ __forceinline__ uint32_t pk2h(float a, float b) {
    union { h2 h; uint32_t u; } t;
    t.h = (h2){ (_Float16)a, (_Float16)b };
    return t.u;
}
__device__ __forceinline__ uint16_t f2h(float a) {
    union { _Float16 h; uint16_t u; } t; t.h = (_Float16)a; return t.u;
}

__device__ __forceinline__ uint64_t sm64(uint64_t x) {
    x += 0x9E3779B97F4A7C15ULL;
    x = (x ^ (x >> 30)) * 0xBF58476D1CE4E5B9ULL;
    x = (x ^ (x >> 27)) * 0x94D049BB133111EBULL;
    return x ^ (x >> 31);
}

__device__ __forceinline__ uint32_t rowz_of(uint32_t f, int dim, int S, int s) {
    uint32_t b = f & 31u;
    uint32_t r = f >> 5;
    uint32_t d, h, w;
    if (dim == 0) {
        w = r & 7u; h = (r >> 3) & 7u; d = (r >> 6) + (uint32_t)s;
    } else if (dim == 1) {
        w = r & 7u; uint32_t q = r >> 3;
        h = q % (uint32_t)S + (uint32_t)s; d = q / (uint32_t)S;
    } else {
        w = r % (uint32_t)S + (uint32_t)s; uint32_t q = r / (uint32_t)S;
        h = q & 7u; d = q >> 3;
    }
    return b * 512u + d * 64u + h * 8u + w;
}

// ---------------- kernels ----------------
__global__ void k_init(float* sums_s, int* cnts_s) {
    int t = blockIdx.x * 256 + threadIdx.x;
    if (t < 1152) { sums_s[t] = 0.f; cnts_s[t] = 0; }
}

// Transpose+cast to fp16, ROW-MAJOR [row=b*512+p][ch] for both z and c.
__global__ __launch_bounds__(256) void k_prep(const float* __restrict__ z,
                                              const float* __restrict__ c,
                                              uint16_t* __restrict__ zh,
                                              uint16_t* __restrict__ cTh) {
    __shared__ float tile[32][65];
    const int t = threadIdx.x;
    const int b = blockIdx.z & 31, isC = blockIdx.z >> 5;
    const float* src = (isC ? c : z) + (size_t)b * 131072;
    const int p0 = blockIdx.x * 64, ch0 = blockIdx.y * 32;
    const int pl = t & 63, cl0 = t >> 6;
    #pragma unroll
    for (int i = 0; i < 8; i++)
        tile[cl0 + i * 4][pl] = src[(ch0 + cl0 + i * 4) * 512 + p0 + pl];
    __syncthreads();
    const int ml = t >> 2, ck = (t & 3) * 8;
    uint4 o;
    o.x = pk2h(tile[ck + 0][ml], tile[ck + 1][ml]);
    o.y = pk2h(tile[ck + 2][ml], tile[ck + 3][ml]);
    o.z = pk2h(tile[ck + 4][ml], tile[ck + 5][ml]);
    o.w = pk2h(tile[ck + 6][ml], tile[ck + 7][ml]);
    uint16_t* dst = isC ? cTh : zh;
    *(uint4*)(dst + (size_t)(b * 512 + p0 + ml) * 256 + ch0 + ck) = o;
}

// W [kk][o][c] f32 -> Whf fp16, 32x32x16 B-fragment order:
//   Whf[((kk*16+ks2)*8+ot)*512 + lane*8 + j] = W[kk][ot*32+(lane&31)][ks2*16+(lane>>5)*8+j]
__global__ __launch_bounds__(256) void k_castw(const float* __restrict__ W,
                                               uint16_t* __restrict__ Whf) {
    const int gid = blockIdx.x * 4 + (threadIdx.x >> 6);   // 0..767
    const int lane = threadIdx.x & 63;
    const int kk = gid >> 7, rem = gid & 127;
    const int ks2 = rem >> 3, ot = rem & 7;
    const int o = ot * 32 + (lane & 31);
    const int cc = ks2 * 16 + (lane >> 5) * 8;
    const float* src = W + ((size_t)kk * 256 + o) * 256 + cc;
    float4 v0 = *(const float4*)src;
    float4 v1 = *(const float4*)(src + 4);
    uint4 out = make_uint4(pk2h(v0.x, v0.y), pk2h(v0.z, v0.w),
                           pk2h(v1.x, v1.y), pk2h(v1.z, v1.w));
    *(uint4*)(Whf + (size_t)gid * 512 + lane * 8) = out;
}

// ZWh[kk][m][o] via 32x32x16 MFMA. Block = 4 waves x 32-row tiles (128 rows).
// B fragments staged once per block into double-buffered LDS (8 KB/step),
// shared by all 4 waves. Writeback LDS-staged -> coalesced dwordx4.
__global__ __launch_bounds__(256, 2) void k_gemm(const uint16_t* __restrict__ zh,
                                                 const uint16_t* __restrict__ Whf,
                                                 uint16_t* __restrict__ ZWh) {
    __shared__ uint16_t Bbuf[2][4096];     // 2 x 8 KB
    __shared__ uint16_t Cbuf[4][4096];     // 4 waves x 8 KB (16 rows x 256)
    const int kk = blockIdx.y;
    const int t = threadIdx.x, lane = t & 63, wv = t >> 6;
    const int m0 = blockIdx.x * 128 + wv * 32;
    const int col = lane & 31, hl = lane >> 5;
    const uint16_t* W32 = Whf + (size_t)kk * 65536;
    const uint16_t* A0 = zh + (size_t)(m0 + col) * 256 + hl * 8;

    f32x16 acc[8];
    #pragma unroll
    for (int i = 0; i < 8; i++)
        #pragma unroll
        for (int jj = 0; jj < 16; jj++) acc[i][jj] = 0.f;

    // stage ks2=0
    {
        const uint16_t* src = W32 + t * 16;
        *(uint4*)(&Bbuf[0][t * 16]) = *(const uint4*)src;
        *(uint4*)(&Bbuf[0][t * 16 + 8]) = *(const uint4*)(src + 8);
    }
    __syncthreads();
    for (int ks2 = 0; ks2 < 16; ks2++) {
        if (ks2 < 15) {
            const uint16_t* src = W32 + (size_t)(ks2 + 1) * 4096 + t * 16;
            uint16_t* db = Bbuf[(ks2 + 1) & 1];
            *(uint4*)(&db[t * 16]) = *(const uint4*)src;
            *(uint4*)(&db[t * 16 + 8]) = *(const uint4*)(src + 8);
        }
        h8 a = *(const h8*)(A0 + ks2 * 16);
        const uint16_t* Bb = Bbuf[ks2 & 1];
        #pragma unroll
        for (int ot = 0; ot < 8; ot++) {
            h8 bv = *(const h8*)(&Bb[ot * 512 + lane * 8]);
            acc[ot] = __builtin_amdgcn_mfma_f32_32x32x16_f16(a, bv, acc[ot], 0, 0, 0);
        }
        __syncthreads();
    }

    // writeback: C/D 32x32 layout row=(reg&3)+8*(reg>>2)+4*hl, col=lane&31
    uint16_t* Lb = Cbuf[wv];
    uint16_t* dstbase = ZWh + ((size_t)kk * 16384 + m0) * 256;
    #pragma unroll
    for (int hh = 0; hh < 2; hh++) {
        #pragma unroll
        for (int ot = 0; ot < 8; ot++)
            #pragma unroll
            for (int rg = 0; rg < 8; rg++) {
                int reg = hh * 8 + rg;
                int row = (reg & 3) + 8 * (reg >> 2) + 4 * hl;   // in [16hh,16hh+16)
                Lb[(row - hh * 16) * 256 + ot * 32 + col] = f2h(acc[ot][reg]);
            }
        const uint4* Lr = (const uint4*)Lb;
        uint4* dst = (uint4*)(dstbase + hh * 16 * 256);
        #pragma unroll
        for (int i = 0; i < 8; i++)
            dst[i * 64 + lane] = Lr[i * 64 + lane];
    }
}

// Score: one wave = 16 positions with SAME batch b, consecutive r (contiguous
// ctx/pos rows). 8 independent negative sets of 16 per group; positions
// 2j,2j+1 use set j. Slotted atomics.
__global__ __launch_bounds__(256) void k_score(const uint16_t* __restrict__ ZWh,
                                               const uint16_t* __restrict__ cTh,
                                               const int* __restrict__ ign,
                                               float* sums_s, int* cnts_s) {
    __shared__ float sbuf[4][288];
    __shared__ float wsum[4], wcnt[4];
    int bid = blockIdx.x;
    int kk = 0, cum = 0;
    for (;;) { int nb = 96 * (6 - kk); if (bid < cum + nb) break; cum += nb; kk++; }
    const int S = 6 - kk, T = S * 2048, s = kk + 2;
    const uint16_t* ZW = ZWh + (size_t)kk * 16384 * 256;

    const int local = bid - cum;               // [0, 96S)
    const int dim = local / (32 * S);
    const int loc2 = local - dim * 32 * S;     // [0, 32S)
    const int term = dim * 6 + kk;

    const int t = threadIdx.x, lane = t & 63, wv = t >> 6;
    const int lm = lane & 15, lq = lane >> 4;
    const uint32_t gidx = (uint32_t)(loc2 * 4 + wv);   // group in [0, 128S)
    const uint32_t b = gidx & 31u;
    const uint32_t rb = gidx >> 5;
    const uint32_t r = rb * 16u + (uint32_t)lm;        // this lane's position r

    uint32_t d, h, w;
    if (dim == 0)      { w = r & 7u; h = (r >> 3) & 7u; d = r >> 6; }
    else if (dim == 1) { w = r & 7u; uint32_t qq = r >> 3; h = qq % (uint32_t)S; d = qq / (uint32_t)S; }
    else               { w = r % (uint32_t)S; uint32_t qq = r / (uint32_t)S; h = qq & 7u; d = qq >> 3; }
    uint32_t pc = d * 64u + h * 8u + w;
    uint32_t pz = pc + (dim == 0 ? (uint32_t)s * 64u : dim == 1 ? (uint32_t)s * 8u : (uint32_t)s);
    uint32_t rowc = b * 512u + pc;
    uint32_t rowz = b * 512u + pz;

    // 8 negative sets; set j, neg slot lm (same for all lq -> valid B-fragment)
    const uint16_t* np[8];
    #pragma unroll
    for (int j = 0; j < 8; j++) {
        uint64_t x = sm64(((uint64_t)term << 40) +
                          (uint64_t)gidx * 128u + (uint64_t)(j * 16 + lm));
        uint32_t nrow = rowz_of((uint32_t)(x >> 32) % (uint32_t)T, dim, S, s);
        np[j] = ZW + (size_t)nrow * 256 + lq * 8;
    }
    const uint16_t* ap = cTh + (size_t)rowc * 256 + lq * 8;
    const uint16_t* pp = ZW + (size_t)rowz * 256 + lq * 8;

    f32x4 accp = (f32x4){0.f, 0.f, 0.f, 0.f};
    f32x4 accn[8];
    #pragma unroll
    for (int j = 0; j < 8; j++) accn[j] = (f32x4){0.f, 0.f, 0.f, 0.f};

    #pragma unroll
    for (int ks = 0; ks < 8; ks++) {
        h8 a = *(const h8*)(ap + ks * 32);
        accp = __builtin_amdgcn_mfma_f32_16x16x32_f16(a, *(const h8*)(pp + ks * 32), accp, 0, 0, 0);
        #pragma unroll
        for (int j = 0; j < 8; j++)
            accn[j] = __builtin_amdgcn_mfma_f32_16x16x32_f16(
                a, *(const h8*)(np[j] + ks * 32), accn[j], 0, 0, 0);
    }

    // stage: position p=lq*4+rr uses set j=p>>1; from accn[j], rows 2j,2j+1
    float* Sb = sbuf[wv];
    #pragma unroll
    for (int j = 0; j < 8; j++) {
        const int rr0 = (j & 1) * 2;
        if (lq == (j >> 1)) {
            Sb[(lq * 4 + rr0) * 17 + lm]     = accn[j][rr0];
            Sb[(lq * 4 + rr0 + 1) * 17 + lm] = accn[j][rr0 + 1];
        }
    }
    if ((lm >> 2) == lq) Sb[272 + lm] = accp[lm & 3];

    // softmax-NLL for position p = lm (4x redundant across lq)
    float dpos = Sb[272 + lm];
    float mx = dpos;
    float scn[16];
    #pragma unroll
    for (int n = 0; n < 16; n++) { scn[n] = Sb[lm * 17 + n]; mx = fmaxf(mx, scn[n]); }
    float e0 = __expf(dpos - mx), sum = e0;
    #pragma unroll
    for (int n = 0; n < 16; n++) sum += __expf(scn[n] - mx);
    float nll = -__logf(e0 / sum + EPSL);

    int mok = (ign[rowc] + ign[rowz]) == 0;
    float v = mok ? nll : 0.f;
    float cm = mok ? 1.f : 0.f;
    #pragma unroll
    for (int st = 1; st < 64; st <<= 1) {
        v  += __shfl_xor(v, st, 64);
        cm += __shfl_xor(cm, st, 64);
    }
    if (lane == 0) { wsum[wv] = v * 0.25f; wcnt[wv] = cm * 0.25f; }
    __syncthreads();
    if (t == 0) {
        float sv = wsum[0] + wsum[1] + wsum[2] + wsum[3];
        float cv = wcnt[0] + wcnt[1] + wcnt[2] + wcnt[3];
        int slot = blockIdx.x & 63;
        atomicAdd(&sums_s[term * 64 + slot], sv);
        atomicAdd(&cnts_s[term * 64 + slot], (int)(cv + 0.5f));
    }
}

__global__ void k_final(const float* __restrict__ sums_s, const int* __restrict__ cnts_s,
                        float* __restrict__ out) {
    __shared__ float ratio[18];
    int t = threadIdx.x;
    if (t < 18) {
        float sv = 0.f; int cv = 0;
        #pragma unroll 8
        for (int i = 0; i < 64; i++) { sv += sums_s[t * 64 + i]; cv += cnts_s[t * 64 + i]; }
        ratio[t] = sv / (float)cv;
    }
    __syncthreads();
    if (t == 0) {
        float tot = 0.f;
        #pragma unroll
        for (int i = 0; i < 18; i++) tot += ratio[i];
        out[0] = tot / 18.f;
    }
}

// ---------------- launch ----------------
extern "C" void kernel_launch(void* const* d_in, const int* in_sizes, int n_in,
                              void* d_out, int out_size, void* d_ws, size_t ws_size,
                              hipStream_t stream) {
    const float* z   = (const float*)d_in[0];
    const float* c   = (const float*)d_in[1];
    const int*   ign = (const int*)d_in[2];
    const float* Wk  = (const float*)d_in[3];

    float* sums_s = (float*)d_ws;                           // 18*64 floats
    int*   cnts_s = (int*)((char*)d_ws + 4608);             // 18*64 ints
    uint16_t* zh  = (uint16_t*)((char*)d_ws + 65536);       // 8 MiB row-major fp16
    uint16_t* cTh = zh  + (size_t)16384 * 256;              // 8 MiB row-major fp16
    uint16_t* Whf = cTh + (size_t)16384 * 256;              // 768 KiB B-frag order
    uint16_t* ZWh = Whf + (size_t)6 * 65536;                // 48 MiB row-major fp16

    hipLaunchKernelGGL(k_init, dim3(5), dim3(256), 0, stream, sums_s, cnts_s);
    hipLaunchKernelGGL(k_prep, dim3(8, 8, 64), dim3(256), 0, stream, z, c, zh, cTh);
    hipLaunchKernelGGL(k_castw, dim3(192), dim3(256), 0, stream, Wk, Whf);
    hipLaunchKernelGGL(k_gemm, dim3(128, 6), dim3(256), 0, stream, zh, Whf, ZWh);
    hipLaunchKernelGGL(k_score, dim3(2016), dim3(256), 0, stream, ZWh, cTh, ign, sums_s, cnts_s);
    hipLaunchKernelGGL(k_final, dim3(1), dim3(64), 0, stream, sums_s, cnts_s, (float*)d_out);
}